// Round 6
// baseline (4384.436 us; speedup 1.0000x reference)
//
#include <hip/hip_runtime.h>
#include <cstdint>
#include <cstddef>

// ---------------------------------------------------------------------------
// Seq2Seq bi-GRU encoder (T=512,B=512,D=64,H=128,L=2) + 24-step GRU decoder.
// R6 = R5 + decoder weight-row fix. k_dec built MFMA B-fragment row bases
// from jj = w*32 + c16 and then added c16 AGAIN at the load -> every decoder
// weight row shifted by +c16 for 15/16 lanes (both layers, all gates).
// Encoder kernels were always correct (n0 = g*128 + w*32 + cc*16, +c16 once).
// Fragment bases now use jw = w*32; jj kept for bias/column addressing.
// Structure otherwise identical to R5.
// ---------------------------------------------------------------------------

typedef __attribute__((ext_vector_type(8))) short short8_t;
typedef __attribute__((ext_vector_type(4))) short short4_t;
typedef __attribute__((ext_vector_type(4))) float f32x4_t;

#define MFMA16(a, b, c) __builtin_amdgcn_mfma_f32_16x16x32_bf16((a), (b), (c), 0, 0, 0)

static __device__ __forceinline__ float bf2f(unsigned short u) {
  unsigned int v = ((unsigned int)u) << 16;
  return __builtin_bit_cast(float, v);
}
static __device__ __forceinline__ unsigned short f2bf(float f) {
  unsigned int x = __builtin_bit_cast(unsigned int, f);
  x += 0x7fffu + ((x >> 16) & 1u);   // round-to-nearest-even
  return (unsigned short)(x >> 16);
}
static __device__ __forceinline__ short8_t ld8(const unsigned short* p) {
  return *reinterpret_cast<const short8_t*>(p);
}
static __device__ __forceinline__ short8_t cvt8f(const float* p) {
  const f32x4_t* v = reinterpret_cast<const f32x4_t*>(p);
  f32x4_t a = v[0], b = v[1];
  short8_t r;
  r[0] = (short)f2bf(a[0]); r[1] = (short)f2bf(a[1]);
  r[2] = (short)f2bf(a[2]); r[3] = (short)f2bf(a[3]);
  r[4] = (short)f2bf(b[0]); r[5] = (short)f2bf(b[1]);
  r[6] = (short)f2bf(b[2]); r[7] = (short)f2bf(b[3]);
  return r;
}
static __device__ __forceinline__ float sigm(float x) { return 1.0f / (1.0f + __expf(-x)); }
static __device__ __forceinline__ float tanh_fast(float y) {
  float t = __expf(-2.0f * fabsf(y));
  float r = (1.0f - t) / (1.0f + t);
  return copysignf(r, y);
}

// ------------- prep: snapshot x[-1,:,0], cast decoder weights ---------------
// dec_Wih1 (2,384,256)=196608 elems; dec_Whh (2,2,384,128)=196608 elems.
__global__ void k_prep(const float* __restrict__ x,
                       const float* __restrict__ dWih1, const float* __restrict__ dWhh,
                       unsigned short* __restrict__ bdWih1, unsigned short* __restrict__ bdWhh,
                       float* __restrict__ x0save) {
  const int n1 = 196608, n2 = 196608;
  int i = blockIdx.x * blockDim.x + threadIdx.x;
  int stride = gridDim.x * blockDim.x;
  for (; i < n1 + n2 + 512; i += stride) {
    if (i < n1) bdWih1[i] = f2bf(dWih1[i]);
    else if (i < n1 + n2) bdWhh[i - n1] = f2bf(dWhh[i - n1]);
    else {
      int b = i - n1 - n2;
      x0save[b] = x[((size_t)511 * 512 + b) * 64];
    }
  }
}

// --------------------- layer-0 scan, gi fused (K=64) ------------------------
__global__ __launch_bounds__(256, 1) void k_scan0(
    const float* x,                         // (512,512,64) fp32 (NOT restrict: aliases Yout)
    const float* __restrict__ Wih,          // enc_Wih0 (2,384,64) fp32
    const float* __restrict__ bih,          // (2,384) layer0
    const float* __restrict__ Whh,          // (2,384,128) layer0
    const float* __restrict__ bhh,          // (2,384) layer0
    unsigned short* Yout,                   // out_f ws buffer (local) or x-overlay (global)
    float* __restrict__ HS,                 // (4,512,128) fp32
    int b_base, int dir, int ytstride) {
  int b0 = b_base + blockIdx.x * 16;
  int yb0 = dir ? b0 : (b0 - b_base);
  int tid = threadIdx.x, w = tid >> 6, lane = tid & 63, q = lane >> 4, c16 = lane & 15;
  __shared__ unsigned short xl[16 * 72];    // x tile bf16 (+8 pad)
  __shared__ unsigned short hl[16 * 136];   // h tile bf16 (+8 pad)
  const float* Wi = Wih + (size_t)dir * 384 * 64;
  const float* Wh = Whh + (size_t)dir * 384 * 128;
  const float* bi = bih + dir * 384;
  const float* bh = bhh + dir * 384;

  short8_t fi[6][2], fh[6][4];
  float brz[4], bni[2], bnh[2];
#pragma unroll
  for (int g = 0; g < 3; g++)
#pragma unroll
    for (int cc = 0; cc < 2; cc++) {
      int f = g * 2 + cc;
      int n0 = g * 128 + w * 32 + cc * 16;
#pragma unroll
      for (int kt = 0; kt < 2; kt++)
        fi[f][kt] = cvt8f(Wi + (size_t)(n0 + c16) * 64 + kt * 32 + q * 8);
#pragma unroll
      for (int kt = 0; kt < 4; kt++)
        fh[f][kt] = cvt8f(Wh + (size_t)(n0 + c16) * 128 + kt * 32 + q * 8);
      if (g < 2) brz[f] = bi[n0 + c16] + bh[n0 + c16];
      else { bni[cc] = bi[n0 + c16]; bnh[cc] = bh[n0 + c16]; }
    }

  float h[2][4];
#pragma unroll
  for (int cc = 0; cc < 2; cc++)
#pragma unroll
    for (int rr = 0; rr < 4; rr++) h[cc][rr] = 0.f;
  for (int i = tid; i < 16 * 136; i += 256) hl[i] = 0;

  int srow = tid >> 4, sc = tid & 15;      // staging/writeback roles
  int prev = -1;
  for (int s = 0; s < 512; s++) {
    int t = dir ? (511 - s) : s;
    {
      const float* xp = x + ((size_t)t * 512 + b0 + srow) * 64 + sc * 4;
      f32x4_t v = *reinterpret_cast<const f32x4_t*>(xp);
      unsigned short* dst = &xl[srow * 72 + sc * 4];
      dst[0] = f2bf(v[0]); dst[1] = f2bf(v[1]); dst[2] = f2bf(v[2]); dst[3] = f2bf(v[3]);
    }
    __syncthreads();                       // B1: xl ready, hl = h_{s-1} complete
    if (prev >= 0) {
      short8_t v = ld8(&hl[srow * 136 + sc * 8]);
      *reinterpret_cast<short8_t*>(
          Yout + ((size_t)prev * ytstride + yb0 + srow) * 128 + sc * 8) = v;
    }
    short8_t ax[2], ah[4];
#pragma unroll
    for (int kt = 0; kt < 2; kt++) ax[kt] = ld8(&xl[c16 * 72 + kt * 32 + q * 8]);
#pragma unroll
    for (int kt = 0; kt < 4; kt++) ah[kt] = ld8(&hl[c16 * 136 + kt * 32 + q * 8]);
    f32x4_t aRZ[4], aNi[2], aNh[2];
#pragma unroll
    for (int f = 0; f < 4; f++) aRZ[f] = (f32x4_t){0.f, 0.f, 0.f, 0.f};
#pragma unroll
    for (int cc = 0; cc < 2; cc++) {
      aNi[cc] = (f32x4_t){0.f, 0.f, 0.f, 0.f};
      aNh[cc] = (f32x4_t){0.f, 0.f, 0.f, 0.f};
    }
#pragma unroll
    for (int kt = 0; kt < 2; kt++) {
#pragma unroll
      for (int f = 0; f < 4; f++) aRZ[f] = MFMA16(ax[kt], fi[f][kt], aRZ[f]);
#pragma unroll
      for (int cc = 0; cc < 2; cc++) aNi[cc] = MFMA16(ax[kt], fi[4 + cc][kt], aNi[cc]);
    }
#pragma unroll
    for (int kt = 0; kt < 4; kt++) {
#pragma unroll
      for (int f = 0; f < 4; f++) aRZ[f] = MFMA16(ah[kt], fh[f][kt], aRZ[f]);
#pragma unroll
      for (int cc = 0; cc < 2; cc++) aNh[cc] = MFMA16(ah[kt], fh[4 + cc][kt], aNh[cc]);
    }
    __syncthreads();                       // B3: all xl/hl reads done
#pragma unroll
    for (int cc = 0; cc < 2; cc++)
#pragma unroll
      for (int rr = 0; rr < 4; rr++) {
        float r = sigm(aRZ[cc][rr] + brz[cc]);
        float z = sigm(aRZ[2 + cc][rr] + brz[2 + cc]);
        float n = tanh_fast(aNi[cc][rr] + bni[cc] + r * (aNh[cc][rr] + bnh[cc]));
        float hn = n + z * (h[cc][rr] - n);
        h[cc][rr] = hn;
        hl[(q * 4 + rr) * 136 + w * 32 + c16 + cc * 16] = f2bf(hn);
      }
    prev = t;
  }
  __syncthreads();
  {
    short8_t v = ld8(&hl[srow * 136 + sc * 8]);
    *reinterpret_cast<short8_t*>(
        Yout + ((size_t)prev * ytstride + yb0 + srow) * 128 + sc * 8) = v;
  }
#pragma unroll
  for (int cc = 0; cc < 2; cc++)
#pragma unroll
    for (int rr = 0; rr < 4; rr++)
      HS[((size_t)dir * 512 + b0 + q * 4 + rr) * 128 + w * 32 + c16 + cc * 16] = h[cc][rr];
}

// ----------------- layer-1 gi chunk GEMM (K=256, A = [outF|outB]) -----------
__global__ __launch_bounds__(256, 1) void k_gi1(
    const unsigned short* __restrict__ OutF,
    const unsigned short* __restrict__ OutB,
    const float* __restrict__ Wih1,         // enc_Wih1 (2,384,256) fp32
    const float* __restrict__ bih1,         // (2,384) layer1
    unsigned short* __restrict__ GIc,
    int t0f, int t0b, int b_base, int Bc, int lb, int CT) {
  int d = blockIdx.y;
  int t0 = d ? t0b : t0f;
  int tid = threadIdx.x, w = tid >> 6, lane = tid & 63, q = lane >> 4, c16 = lane & 15;
  int m0 = blockIdx.x * 64 + w * 16;        // chunk-local row tile base (16-aligned)
  __shared__ unsigned short sw[384 * 40];   // 32-wide K-chunk of Wih1 (+8 pad)
  const float* Wd = Wih1 + (size_t)d * 384 * 256;

  f32x4_t acc[24];
#pragma unroll
  for (int i = 0; i < 24; i++) acc[i] = (f32x4_t){0.f, 0.f, 0.f, 0.f};

  int tl = m0 >> lb;
  int bl = (m0 & (Bc - 1)) + c16;
  size_t rF = (size_t)(t0 + tl) * Bc + bl;              // OutF local row
  size_t rB = (size_t)(t0 + tl) * 512 + b_base + bl;    // OutB global row

  for (int kc = 0; kc < 8; kc++) {
    __syncthreads();
    for (int g = tid; g < 1536; g += 256) {
      int n = g >> 2, kk = (g & 3) * 8;
      *reinterpret_cast<short8_t*>(&sw[n * 40 + kk]) = cvt8f(Wd + (size_t)n * 256 + kc * 32 + kk);
    }
    __syncthreads();
    int kg = kc * 32 + q * 8;
    short8_t a = (kg < 128) ? ld8(OutF + rF * 128 + kg) : ld8(OutB + rB * 128 + (kg - 128));
#pragma unroll
    for (int n = 0; n < 24; n++) {
      short8_t b = ld8(&sw[(n * 16 + c16) * 40 + q * 8]);
      acc[n] = MFMA16(a, b, acc[n]);
    }
  }
  int bl0 = (m0 & (Bc - 1)) + q * 4;
#pragma unroll
  for (int n = 0; n < 24; n++) {
    int col = n * 16 + c16;
    float bv = bih1[d * 384 + col];
    short4_t v;
#pragma unroll
    for (int rr = 0; rr < 4; rr++) v[rr] = (short)f2bf(acc[n][rr] + bv);
    *reinterpret_cast<short4_t*>(
        &GIc[(((size_t)d * CT + tl) * 384 + col) * (size_t)Bc + bl0]) = v;
  }
}

// --------------------------- layer-1 scan chunk -----------------------------
__global__ __launch_bounds__(256, 1) void k_scan1(
    const unsigned short* __restrict__ GIc,
    const float* __restrict__ Whh,          // layer1 (2,384,128) fp32
    const float* __restrict__ bhh,          // layer1 (2,384) fp32
    float* __restrict__ HS,
    int b_base, int Bc, int CT, int first) {
  int d = blockIdx.y;
  int b0l = blockIdx.x * 16;
  int b0 = b_base + b0l;
  int tid = threadIdx.x, w = tid >> 6, lane = tid & 63, q = lane >> 4, c16 = lane & 15;
  __shared__ unsigned short hl[16 * 136];
  const float* Wd = Whh + (size_t)d * 384 * 128;
  const float* bhd = bhh + d * 384;

  short8_t fh[6][4];
  float bh[6];
#pragma unroll
  for (int g = 0; g < 3; g++)
#pragma unroll
    for (int cc = 0; cc < 2; cc++) {
      int f = g * 2 + cc;
      int n0 = g * 128 + w * 32 + cc * 16;
      bh[f] = bhd[n0 + c16];
#pragma unroll
      for (int kt = 0; kt < 4; kt++)
        fh[f][kt] = cvt8f(Wd + (size_t)(n0 + c16) * 128 + kt * 32 + q * 8);
    }

  float h[2][4];
  if (first) {
#pragma unroll
    for (int cc = 0; cc < 2; cc++)
#pragma unroll
      for (int rr = 0; rr < 4; rr++) h[cc][rr] = 0.f;
    for (int i = tid; i < 16 * 136; i += 256) hl[i] = 0;
  } else {
#pragma unroll
    for (int cc = 0; cc < 2; cc++)
#pragma unroll
      for (int rr = 0; rr < 4; rr++) {
        int row = q * 4 + rr, j = w * 32 + c16 + cc * 16;
        float v = HS[((size_t)(2 + d) * 512 + b0 + row) * 128 + j];
        h[cc][rr] = v;
        hl[row * 136 + j] = f2bf(v);
      }
  }

  for (int s = 0; s < CT; s++) {
    int sl = d ? (CT - 1 - s) : s;
    __syncthreads();                       // hl stable
    float gu[6][4];
#pragma unroll
    for (int g = 0; g < 3; g++)
#pragma unroll
      for (int cc = 0; cc < 2; cc++) {
        int f = g * 2 + cc;
        int col = g * 128 + w * 32 + c16 + cc * 16;
        const unsigned short* p =
            GIc + (((size_t)d * CT + sl) * 384 + col) * (size_t)Bc + b0l + q * 4;
        short4_t v = *reinterpret_cast<const short4_t*>(p);
#pragma unroll
        for (int rr = 0; rr < 4; rr++) gu[f][rr] = bf2f((unsigned short)v[rr]);
      }
    short8_t ah[4];
#pragma unroll
    for (int kt = 0; kt < 4; kt++) ah[kt] = ld8(&hl[c16 * 136 + kt * 32 + q * 8]);
    f32x4_t acc[6];
#pragma unroll
    for (int f = 0; f < 6; f++) acc[f] = (f32x4_t){0.f, 0.f, 0.f, 0.f};
#pragma unroll
    for (int kt = 0; kt < 4; kt++)
#pragma unroll
      for (int f = 0; f < 6; f++) acc[f] = MFMA16(ah[kt], fh[f][kt], acc[f]);
    __syncthreads();                       // hl reads done
#pragma unroll
    for (int cc = 0; cc < 2; cc++)
#pragma unroll
      for (int rr = 0; rr < 4; rr++) {
        float r = sigm(gu[cc][rr] + acc[cc][rr] + bh[cc]);
        float z = sigm(gu[2 + cc][rr] + acc[2 + cc][rr] + bh[2 + cc]);
        float n = tanh_fast(gu[4 + cc][rr] + r * (acc[4 + cc][rr] + bh[4 + cc]));
        float hn = n + z * (h[cc][rr] - n);
        h[cc][rr] = hn;
        hl[(q * 4 + rr) * 136 + w * 32 + c16 + cc * 16] = f2bf(hn);
      }
  }
#pragma unroll
  for (int cc = 0; cc < 2; cc++)
#pragma unroll
    for (int rr = 0; rr < 4; rr++)
      HS[((size_t)(2 + d) * 512 + b0 + q * 4 + rr) * 128 + w * 32 + c16 + cc * 16] = h[cc][rr];
}

// ------------------------------- decoder ------------------------------------
__global__ __launch_bounds__(256, 1) void k_dec(
    const float* __restrict__ x0save,        // (512)
    const float* __restrict__ HS,            // (4,512,128) = [l0f,l0b,l1f,l1b]
    const unsigned short* __restrict__ Whh,  // dec (2,2,384,128) bf16
    const unsigned short* __restrict__ Wih1, // dec (2,384,256) bf16
    const float* __restrict__ Wih0,          // dec (2,384,1) fp32
    const float* __restrict__ bih,           // (2,2,384)
    const float* __restrict__ bhh,           // (2,2,384)
    const float* __restrict__ fc_w,          // (256) fp32
    const float* __restrict__ fcb,           // (1)
    float* __restrict__ out) {               // (24,512)
  int b0 = blockIdx.x * 16;
  int tid = threadIdx.x, w = tid >> 6, lane = tid & 63, q = lane >> 4, c16 = lane & 15;
  __shared__ unsigned short hc0[16 * 264];
  __shared__ unsigned short hc1[16 * 264];
  __shared__ float x0s[16];
  __shared__ float fcwf[256];
  int jj = w * 32 + c16;   // actual h-column (biases, LDS addressing)
  int jw = w * 32;         // wave column base (MFMA B-frag row bases; +c16 at load)

  float hs[4][2][4];
#pragma unroll
  for (int cell = 0; cell < 4; cell++)
#pragma unroll
    for (int cc = 0; cc < 2; cc++)
#pragma unroll
      for (int rr = 0; rr < 4; rr++) {
        int row = q * 4 + rr, j = jj + cc * 16;
        float v = HS[((size_t)cell * 512 + b0 + row) * 128 + j];
        hs[cell][cc][rr] = v;
        unsigned short bv = f2bf(v);
        unsigned short* tile = (cell < 2) ? hc0 : hc1;
        tile[row * 264 + (cell & 1) * 128 + j] = bv;
      }
  if (tid < 16) x0s[tid] = x0save[b0 + tid];
  fcwf[tid] = fc_w[tid];

  float w0c[2][2][3], bi0[2][2][3], bh0[2][2][3], bi1[2][2][3], bh1[2][2][3];
#pragma unroll
  for (int d = 0; d < 2; d++)
#pragma unroll
    for (int cc = 0; cc < 2; cc++)
#pragma unroll
      for (int g = 0; g < 3; g++) {
        int col = g * 128 + jj + cc * 16;
        w0c[d][cc][g] = Wih0[d * 384 + col];
        bi0[d][cc][g] = bih[d * 384 + col];
        bh0[d][cc][g] = bhh[d * 384 + col];
        bi1[d][cc][g] = bih[(2 + d) * 384 + col];
        bh1[d][cc][g] = bhh[(2 + d) * 384 + col];
      }
  __syncthreads();

  for (int st = 0; st < 24; st++) {
    // ---- layer 0 (input = scalar x0, two cells) ----
    float hn0[2][2][4];
#pragma unroll
    for (int d = 0; d < 2; d++) {
      const unsigned short* Wd = Whh + (size_t)d * 384 * 128;
      short8_t a0[4];
#pragma unroll
      for (int kt = 0; kt < 4; kt++)
        a0[kt] = ld8(&hc0[c16 * 264 + d * 128 + kt * 32 + q * 8]);
      f32x4_t acc[6];
#pragma unroll
      for (int f = 0; f < 6; f++) acc[f] = (f32x4_t){0.f, 0.f, 0.f, 0.f};
#pragma unroll
      for (int kt = 0; kt < 4; kt++)
#pragma unroll
        for (int g = 0; g < 3; g++)
#pragma unroll
          for (int cc = 0; cc < 2; cc++) {
            int f = g * 2 + cc, n0 = g * 128 + jw + cc * 16;   // FIXED: jw not jj
            acc[f] = MFMA16(a0[kt], ld8(Wd + (size_t)(n0 + c16) * 128 + kt * 32 + q * 8), acc[f]);
          }
#pragma unroll
      for (int cc = 0; cc < 2; cc++)
#pragma unroll
        for (int rr = 0; rr < 4; rr++) {
          float xin = x0s[q * 4 + rr];
          float r = sigm(xin * w0c[d][cc][0] + bi0[d][cc][0] + acc[cc][rr] + bh0[d][cc][0]);
          float z = sigm(xin * w0c[d][cc][1] + bi0[d][cc][1] + acc[2 + cc][rr] + bh0[d][cc][1]);
          float n = tanh_fast(xin * w0c[d][cc][2] + bi0[d][cc][2] +
                              r * (acc[4 + cc][rr] + bh0[d][cc][2]));
          float hv = n + z * (hs[d][cc][rr] - n);
          hn0[d][cc][rr] = hv;
          hs[d][cc][rr] = hv;
        }
    }
    __syncthreads();
#pragma unroll
    for (int d = 0; d < 2; d++)
#pragma unroll
      for (int cc = 0; cc < 2; cc++)
#pragma unroll
        for (int rr = 0; rr < 4; rr++)
          hc0[(q * 4 + rr) * 264 + d * 128 + jj + cc * 16] = f2bf(hn0[d][cc][rr]);
    __syncthreads();

    // ---- layer 1 (input = hc0 concat, two cells) ----
    short8_t ai[8];
#pragma unroll
    for (int kt = 0; kt < 8; kt++) ai[kt] = ld8(&hc0[c16 * 264 + kt * 32 + q * 8]);
    float hn1[2][2][4];
#pragma unroll
    for (int d = 0; d < 2; d++) {
      const unsigned short* Wh = Whh + (size_t)(2 + d) * 384 * 128;
      const unsigned short* Wi = Wih1 + (size_t)d * 384 * 256;
      short8_t ah[4];
#pragma unroll
      for (int kt = 0; kt < 4; kt++)
        ah[kt] = ld8(&hc1[c16 * 264 + d * 128 + kt * 32 + q * 8]);
      f32x4_t aRZ[4], aNi[2], aNh[2];
#pragma unroll
      for (int f = 0; f < 4; f++) aRZ[f] = (f32x4_t){0.f, 0.f, 0.f, 0.f};
#pragma unroll
      for (int cc = 0; cc < 2; cc++) {
        aNi[cc] = (f32x4_t){0.f, 0.f, 0.f, 0.f};
        aNh[cc] = (f32x4_t){0.f, 0.f, 0.f, 0.f};
      }
#pragma unroll
      for (int kt = 0; kt < 8; kt++) {
#pragma unroll
        for (int f = 0; f < 4; f++) {
          int n0 = (f >> 1) * 128 + jw + (f & 1) * 16;         // FIXED: jw not jj
          aRZ[f] = MFMA16(ai[kt], ld8(Wi + (size_t)(n0 + c16) * 256 + kt * 32 + q * 8), aRZ[f]);
        }
#pragma unroll
        for (int cc = 0; cc < 2; cc++) {
          int n0 = 256 + jw + cc * 16;                          // FIXED: jw not jj
          aNi[cc] = MFMA16(ai[kt], ld8(Wi + (size_t)(n0 + c16) * 256 + kt * 32 + q * 8), aNi[cc]);
        }
      }
#pragma unroll
      for (int kt = 0; kt < 4; kt++) {
#pragma unroll
        for (int f = 0; f < 4; f++) {
          int n0 = (f >> 1) * 128 + jw + (f & 1) * 16;         // FIXED: jw not jj
          aRZ[f] = MFMA16(ah[kt], ld8(Wh + (size_t)(n0 + c16) * 128 + kt * 32 + q * 8), aRZ[f]);
        }
#pragma unroll
        for (int cc = 0; cc < 2; cc++) {
          int n0 = 256 + jw + cc * 16;                          // FIXED: jw not jj
          aNh[cc] = MFMA16(ah[kt], ld8(Wh + (size_t)(n0 + c16) * 128 + kt * 32 + q * 8), aNh[cc]);
        }
      }
#pragma unroll
      for (int cc = 0; cc < 2; cc++)
#pragma unroll
        for (int rr = 0; rr < 4; rr++) {
          float r = sigm(aRZ[cc][rr] + bi1[d][cc][0] + bh1[d][cc][0]);
          float z = sigm(aRZ[2 + cc][rr] + bi1[d][cc][1] + bh1[d][cc][1]);
          float n = tanh_fast(aNi[cc][rr] + bi1[d][cc][2] + r * (aNh[cc][rr] + bh1[d][cc][2]));
          float hv = n + z * (hs[2 + d][cc][rr] - n);
          hn1[d][cc][rr] = hv;
          hs[2 + d][cc][rr] = hv;
        }
    }
    __syncthreads();
#pragma unroll
    for (int d = 0; d < 2; d++)
#pragma unroll
      for (int cc = 0; cc < 2; cc++)
#pragma unroll
        for (int rr = 0; rr < 4; rr++)
          hc1[(q * 4 + rr) * 264 + d * 128 + jj + cc * 16] = f2bf(hn1[d][cc][rr]);
    __syncthreads();

    // ---- fc -> pred, feed back (wave 0 only) ----
    if (w == 0) {
      float s = 0.f;
#pragma unroll
      for (int i = 0; i < 8; i++) {
        short8_t hv = ld8(&hc1[c16 * 264 + q * 64 + i * 8]);
#pragma unroll
        for (int e = 0; e < 8; e++)
          s += bf2f((unsigned short)hv[e]) * fcwf[q * 64 + i * 8 + e];
      }
      s += __shfl_xor(s, 16);
      s += __shfl_xor(s, 32);
      if (q == 0) {
        float pred = s + fcb[0];
        x0s[c16] = pred;
        out[(size_t)st * 512 + b0 + c16] = pred;
      }
    }
    __syncthreads();
  }
}

// ---------------------------------------------------------------------------
extern "C" void kernel_launch(void* const* d_in, const int* in_sizes, int n_in,
                              void* d_out, int out_size, void* d_ws, size_t ws_size,
                              hipStream_t stream) {
  const float* x     = (const float*)d_in[0];
  const float* eWih0 = (const float*)d_in[1];
  const float* eWih1 = (const float*)d_in[2];
  const float* eWhh  = (const float*)d_in[3];
  const float* ebih  = (const float*)d_in[4];
  const float* ebhh  = (const float*)d_in[5];
  const float* dWih0 = (const float*)d_in[6];
  const float* dWih1 = (const float*)d_in[7];
  const float* dWhh  = (const float*)d_in[8];
  const float* dbih  = (const float*)d_in[9];
  const float* dbhh  = (const float*)d_in[10];
  const float* fc_w  = (const float*)d_in[11];
  const float* fc_b  = (const float*)d_in[12];
  float* out = (float*)d_out;
  (void)in_sizes; (void)n_in; (void)out_size;

  // ---- budget ladder (GIc = CT*Bc*3072 bytes: 2 dirs x CT x 384 x Bc bf16) --
  const size_t fixedB = 2048 + 1048576 + 393216 + 393216 + 4096;
  int Bc = 16, CT = 8;
  {
    const int bcs[6] = {512, 256, 128, 64, 32, 16};
    for (int i = 0; i < 6; i++) {
      size_t base = fixedB + (size_t)bcs[i] * 131072;            // + OutF bytes
      if (base + (size_t)bcs[i] * 3072 * 16 <= ws_size) {        // + GIc @ CT=16
        Bc = bcs[i];
        CT = 128;
        while (CT > 16 && base + (size_t)Bc * 3072 * CT > ws_size) CT >>= 1;
        break;
      }
    }
  }
  int lb = 0;
  while ((1 << lb) < Bc) lb++;

  char* ws = (char*)d_ws;
  size_t off = 0;
  auto alloc = [&](size_t bytes) -> char* {
    off = (off + 255) & ~(size_t)255;
    char* p = ws + off;
    off += bytes;
    return p;
  };
  float* x0save          = (float*)alloc(2048);
  float* HS              = (float*)alloc(1048576);
  unsigned short* bdWih1 = (unsigned short*)alloc(393216);   // 196608 elems
  unsigned short* bdWhh  = (unsigned short*)alloc(393216);   // 196608 elems
  unsigned short* OutF   = (unsigned short*)alloc((size_t)Bc * 131072);
  unsigned short* GIc    = (unsigned short*)alloc((size_t)CT * Bc * 3072);
  unsigned short* OutB   = (unsigned short*)d_in[0];   // byte-exact x overlay (global rows)

  dim3 blk(256);
  k_prep<<<1539, blk, 0, stream>>>(x, dWih1, dWhh, bdWih1, bdWhh, x0save);

  int nchunks = 512 / Bc;
  int phases = 512 / CT;
  for (int c = 0; c < nchunks; c++) {
    int b_base = c * Bc;
    k_scan0<<<dim3(Bc / 16), blk, 0, stream>>>(x, eWih0, ebih, eWhh, ebhh,
                                               OutF, HS, b_base, 0, Bc);
    k_scan0<<<dim3(Bc / 16), blk, 0, stream>>>(x, eWih0, ebih, eWhh, ebhh,
                                               OutB, HS, b_base, 1, 512);
    for (int p = 0; p < phases; p++) {
      int t0f = CT * p;
      int t0b = 512 - CT * (p + 1);
      k_gi1<<<dim3(CT * Bc / 64, 2), blk, 0, stream>>>(OutF, OutB, eWih1, ebih + 768,
                                                       GIc, t0f, t0b, b_base, Bc, lb, CT);
      k_scan1<<<dim3(Bc / 16, 2), blk, 0, stream>>>(GIc, eWhh + (size_t)2 * 384 * 128,
                                                    ebhh + 768, HS, b_base, Bc, CT,
                                                    (p == 0) ? 1 : 0);
    }
  }
  k_dec<<<dim3(32), blk, 0, stream>>>(x0save, HS, bdWhh, bdWih1, dWih0, dbih, dbhh,
                                      fc_w, fc_b, out);
}

// Round 8
// 2822.413 us; speedup vs baseline: 1.5534x; 1.5534x over previous
//
#include <hip/hip_runtime.h>
#include <cstdint>
#include <cstddef>

// ---------------------------------------------------------------------------
// Seq2Seq bi-GRU encoder (T=512,B=512,D=64,H=128,L=2) + 24-step GRU decoder.
// R8. R7 aborted on an arithmetic error: each scan0 output dir is 67.1MB
// (512*512 x 128 bf16), NOT 33.5 — the x buffer holds exactly ONE dir.
// Plan (all sizes proven against ws evidence ws in [48.0, 94.1) MB):
//  - scan0-fwd -> OutF in ws (Bc*131072 B); scan0-bwd -> OutB overlays x
//    byte-exact (solo dispatch, within-block write-after-read; R6-proven).
//  - scan1: dirs merged in one dispatch, gi1 fused (Wih1/Whh1 frags in
//    VGPRs, 512-thr blocks), reads OutF (chunk-local) + OutB (global).
//  - all scans software-pipelined: double-buffered LDS, ONE barrier/step,
//    next tile prefetched into registers behind the MFMA chain.
//  - ws-keyed ladder: Bc=512 (1 chunk, 5 dispatches) if ws >= ~69MB,
//    else Bc=256 (2 chunks, 8 dispatches). k_dec unchanged (R6-verified).
// ---------------------------------------------------------------------------

typedef __attribute__((ext_vector_type(8))) short short8_t;
typedef __attribute__((ext_vector_type(4))) short short4_t;
typedef __attribute__((ext_vector_type(4))) float f32x4_t;

#define MFMA16(a, b, c) __builtin_amdgcn_mfma_f32_16x16x32_bf16((a), (b), (c), 0, 0, 0)

static __device__ __forceinline__ float bf2f(unsigned short u) {
  unsigned int v = ((unsigned int)u) << 16;
  return __builtin_bit_cast(float, v);
}
static __device__ __forceinline__ unsigned short f2bf(float f) {
  unsigned int x = __builtin_bit_cast(unsigned int, f);
  x += 0x7fffu + ((x >> 16) & 1u);   // round-to-nearest-even
  return (unsigned short)(x >> 16);
}
static __device__ __forceinline__ short8_t ld8(const unsigned short* p) {
  return *reinterpret_cast<const short8_t*>(p);
}
static __device__ __forceinline__ short8_t cvt8f(const float* p) {
  const f32x4_t* v = reinterpret_cast<const f32x4_t*>(p);
  f32x4_t a = v[0], b = v[1];
  short8_t r;
  r[0] = (short)f2bf(a[0]); r[1] = (short)f2bf(a[1]);
  r[2] = (short)f2bf(a[2]); r[3] = (short)f2bf(a[3]);
  r[4] = (short)f2bf(b[0]); r[5] = (short)f2bf(b[1]);
  r[6] = (short)f2bf(b[2]); r[7] = (short)f2bf(b[3]);
  return r;
}
static __device__ __forceinline__ float sigm(float x) { return 1.0f / (1.0f + __expf(-x)); }
static __device__ __forceinline__ float tanh_fast(float y) {
  float t = __expf(-2.0f * fabsf(y));
  float r = (1.0f - t) / (1.0f + t);
  return copysignf(r, y);
}

// ------------- prep: cast decoder weights, snapshot x[-1,:,0] ---------------
__global__ void k_prep(const float* __restrict__ x,
                       const float* __restrict__ dWih1, const float* __restrict__ dWhh,
                       unsigned short* __restrict__ bdWih1, unsigned short* __restrict__ bdWhh,
                       float* __restrict__ x0save) {
  const int NW = 24576;   // 196608 elems / 8
  int i = blockIdx.x * blockDim.x + threadIdx.x;
  if (i < NW) {
    *reinterpret_cast<short8_t*>(bdWih1 + (size_t)i * 8) = cvt8f(dWih1 + (size_t)i * 8);
  } else if (i < 2 * NW) {
    int j = i - NW;
    *reinterpret_cast<short8_t*>(bdWhh + (size_t)j * 8) = cvt8f(dWhh + (size_t)j * 8);
  } else if (i < 2 * NW + 512) {
    int b = i - 2 * NW;
    x0save[b] = x[((size_t)511 * 512 + b) * 64];
  }
}

// ---- layer-0 scan, gi fused (K=64), one dir, pipelined ---------------------
// grid (Bc/16). Block = 16 batch rows, 4 waves; wave w owns h-cols
// [w*32,w*32+32). Double-buffered xl/hl, ONE barrier/step, x prefetched.
// dir=1 writes Yout over the x rows it already consumed (byte-exact overlay).
__global__ __launch_bounds__(256, 1) void k_scan0(
    const float* x,                         // (512,512,64) fp32 (aliases Yout for dir=1)
    const float* __restrict__ Wih,          // enc_Wih0 (2,384,64) fp32
    const float* __restrict__ bih,          // (2,384) layer0
    const float* __restrict__ Whh,          // (2,384,128) layer0
    const float* __restrict__ bhh,          // (2,384) layer0
    unsigned short* Yout,                   // OutF(ws, stride Bc) or OutB(x, stride 512)
    float* __restrict__ HS,                 // (4,512,128) fp32
    int b_base, int dir, int ytstride) {
  int b0 = b_base + blockIdx.x * 16;
  int yb0 = (dir ? b_base : 0) + blockIdx.x * 16;
  int tid = threadIdx.x, w = tid >> 6, lane = tid & 63, q = lane >> 4, c16 = lane & 15;
  __shared__ unsigned short xl[2][16 * 72];    // x tile bf16 (+8 pad)
  __shared__ unsigned short hl[2][16 * 136];   // h tile bf16 (+8 pad)
  const float* Wi = Wih + (size_t)dir * 384 * 64;
  const float* Wh = Whh + (size_t)dir * 384 * 128;
  const float* bi = bih + dir * 384;
  const float* bh = bhh + dir * 384;

  short8_t fi[6][2], fh[6][4];
  float brz[4], bni[2], bnh[2];
#pragma unroll
  for (int g = 0; g < 3; g++)
#pragma unroll
    for (int cc = 0; cc < 2; cc++) {
      int f = g * 2 + cc;
      int n0 = g * 128 + w * 32 + cc * 16;
#pragma unroll
      for (int kt = 0; kt < 2; kt++)
        fi[f][kt] = cvt8f(Wi + (size_t)(n0 + c16) * 64 + kt * 32 + q * 8);
#pragma unroll
      for (int kt = 0; kt < 4; kt++)
        fh[f][kt] = cvt8f(Wh + (size_t)(n0 + c16) * 128 + kt * 32 + q * 8);
      if (g < 2) brz[f] = bi[n0 + c16] + bh[n0 + c16];
      else { bni[cc] = bi[n0 + c16]; bnh[cc] = bh[n0 + c16]; }
    }

  float h[2][4];
#pragma unroll
  for (int cc = 0; cc < 2; cc++)
#pragma unroll
    for (int rr = 0; rr < 4; rr++) h[cc][rr] = 0.f;
  for (int i = tid; i < 16 * 136; i += 256) hl[0][i] = 0;

  int srow = tid >> 4, sc = tid & 15;          // staging/writeback roles
  {                                            // stage xl[0] for first t
    int t0 = dir ? 511 : 0;
    f32x4_t v = *reinterpret_cast<const f32x4_t*>(
        x + ((size_t)t0 * 512 + b0 + srow) * 64 + sc * 4);
    unsigned short* dst = &xl[0][srow * 72 + sc * 4];
    dst[0] = f2bf(v[0]); dst[1] = f2bf(v[1]); dst[2] = f2bf(v[2]); dst[3] = f2bf(v[3]);
  }
  __syncthreads();

  for (int s = 0; s < 512; s++) {
    int cur = s & 1, nxt = cur ^ 1;
    if (s > 0) {                               // Yout for h(s-1), held in hl[cur]
      int tp = dir ? (512 - s) : (s - 1);
      short8_t v = ld8(&hl[cur][srow * 136 + sc * 8]);
      *reinterpret_cast<short8_t*>(
          Yout + ((size_t)tp * ytstride + yb0 + srow) * 128 + sc * 8) = v;
    }
    f32x4_t xv;                                // prefetch next x tile
    if (s < 511) {
      int tn = dir ? (510 - s) : (s + 1);
      xv = *reinterpret_cast<const f32x4_t*>(
          x + ((size_t)tn * 512 + b0 + srow) * 64 + sc * 4);
    }
    short8_t ax[2], ah[4];
#pragma unroll
    for (int kt = 0; kt < 2; kt++) ax[kt] = ld8(&xl[cur][c16 * 72 + kt * 32 + q * 8]);
#pragma unroll
    for (int kt = 0; kt < 4; kt++) ah[kt] = ld8(&hl[cur][c16 * 136 + kt * 32 + q * 8]);
    f32x4_t aRZ[4], aNi[2], aNh[2];
#pragma unroll
    for (int f = 0; f < 4; f++) aRZ[f] = (f32x4_t){0.f, 0.f, 0.f, 0.f};
#pragma unroll
    for (int cc = 0; cc < 2; cc++) {
      aNi[cc] = (f32x4_t){0.f, 0.f, 0.f, 0.f};
      aNh[cc] = (f32x4_t){0.f, 0.f, 0.f, 0.f};
    }
#pragma unroll
    for (int kt = 0; kt < 2; kt++) {
#pragma unroll
      for (int f = 0; f < 4; f++) aRZ[f] = MFMA16(ax[kt], fi[f][kt], aRZ[f]);
#pragma unroll
      for (int cc = 0; cc < 2; cc++) aNi[cc] = MFMA16(ax[kt], fi[4 + cc][kt], aNi[cc]);
    }
#pragma unroll
    for (int kt = 0; kt < 4; kt++) {
#pragma unroll
      for (int f = 0; f < 4; f++) aRZ[f] = MFMA16(ah[kt], fh[f][kt], aRZ[f]);
#pragma unroll
      for (int cc = 0; cc < 2; cc++) aNh[cc] = MFMA16(ah[kt], fh[4 + cc][kt], aNh[cc]);
    }
#pragma unroll
    for (int cc = 0; cc < 2; cc++)
#pragma unroll
      for (int rr = 0; rr < 4; rr++) {
        float r = sigm(aRZ[cc][rr] + brz[cc]);
        float z = sigm(aRZ[2 + cc][rr] + brz[2 + cc]);
        float n = tanh_fast(aNi[cc][rr] + bni[cc] + r * (aNh[cc][rr] + bnh[cc]));
        float hn = n + z * (h[cc][rr] - n);
        h[cc][rr] = hn;
        hl[nxt][(q * 4 + rr) * 136 + w * 32 + c16 + cc * 16] = f2bf(hn);
      }
    if (s < 511) {
      unsigned short* dst = &xl[nxt][srow * 72 + sc * 4];
      dst[0] = f2bf(xv[0]); dst[1] = f2bf(xv[1]); dst[2] = f2bf(xv[2]); dst[3] = f2bf(xv[3]);
    }
    __syncthreads();
  }
  {                                            // final Yout row (step 511's h in hl[0])
    int tp = dir ? 0 : 511;
    short8_t v = ld8(&hl[0][srow * 136 + sc * 8]);
    *reinterpret_cast<short8_t*>(
        Yout + ((size_t)tp * ytstride + yb0 + srow) * 128 + sc * 8) = v;
  }
#pragma unroll
  for (int cc = 0; cc < 2; cc++)
#pragma unroll
    for (int rr = 0; rr < 4; rr++)
      HS[((size_t)dir * 512 + b0 + q * 4 + rr) * 128 + w * 32 + c16 + cc * 16] = h[cc][rr];
}

// ---- layer-1 scan, gi fused (K=256 = [OutF||OutB]), both dirs, pipelined ---
// grid (Bc/16, 2). Block = 512 thr (8 waves); wave w owns h-cols [w*16,+16).
__global__ __launch_bounds__(512, 1) void k_scan1(
    const unsigned short* __restrict__ OutF,  // ws, row = t*Bc + local b
    const unsigned short* __restrict__ OutB,  // x overlay, row = t*512 + global b
    const float* __restrict__ Wih1,           // enc_Wih1 (2,384,256) fp32
    const float* __restrict__ bih1,           // (2,384) layer1
    const float* __restrict__ Whh1,           // (2,384,128) layer1
    const float* __restrict__ bhh1,           // (2,384) layer1
    float* __restrict__ HS,
    int b_base, int Bc) {
  int dir = blockIdx.y;
  int b0l = blockIdx.x * 16;
  int tid = threadIdx.x, w = tid >> 6, lane = tid & 63, q = lane >> 4, c16 = lane & 15;
  __shared__ unsigned short il[2][16 * 264];   // input tile (256 + 8 pad)
  __shared__ unsigned short hl[2][16 * 136];
  const float* Wi = Wih1 + (size_t)dir * 384 * 256;
  const float* Wh = Whh1 + (size_t)dir * 384 * 128;
  const float* bi = bih1 + dir * 384;
  const float* bh = bhh1 + dir * 384;

  short8_t fi[3][8], fh[3][4];
  float brz[2], bni, bnh;
#pragma unroll
  for (int g = 0; g < 3; g++) {
    int n0 = g * 128 + w * 16;
#pragma unroll
    for (int kt = 0; kt < 8; kt++)
      fi[g][kt] = cvt8f(Wi + (size_t)(n0 + c16) * 256 + kt * 32 + q * 8);
#pragma unroll
    for (int kt = 0; kt < 4; kt++)
      fh[g][kt] = cvt8f(Wh + (size_t)(n0 + c16) * 128 + kt * 32 + q * 8);
    if (g < 2) brz[g] = bi[n0 + c16] + bh[n0 + c16];
    else { bni = bi[n0 + c16]; bnh = bh[n0 + c16]; }
  }

  float h[4] = {0.f, 0.f, 0.f, 0.f};
  for (int i = tid; i < 16 * 136; i += 512) hl[0][i] = 0;

  int srow = tid >> 5, sc = tid & 31;          // staging: 16 rows x 32 col-chunks
  {                                            // stage il[0] for first t
    int t0 = dir ? 511 : 0;
    short8_t v = (sc < 16)
        ? ld8(OutF + ((size_t)t0 * Bc + b0l + srow) * 128 + sc * 8)
        : ld8(OutB + ((size_t)t0 * 512 + b_base + b0l + srow) * 128 + (sc - 16) * 8);
    *reinterpret_cast<short8_t*>(&il[0][srow * 264 + sc * 8]) = v;
  }
  __syncthreads();

  for (int s = 0; s < 512; s++) {
    int cur = s & 1, nxt = cur ^ 1;
    short8_t iv;
    if (s < 511) {                             // prefetch next input tile
      int tn = dir ? (510 - s) : (s + 1);
      iv = (sc < 16)
          ? ld8(OutF + ((size_t)tn * Bc + b0l + srow) * 128 + sc * 8)
          : ld8(OutB + ((size_t)tn * 512 + b_base + b0l + srow) * 128 + (sc - 16) * 8);
    }
    f32x4_t aI[3], aH[3];
#pragma unroll
    for (int g = 0; g < 3; g++) {
      aI[g] = (f32x4_t){0.f, 0.f, 0.f, 0.f};
      aH[g] = (f32x4_t){0.f, 0.f, 0.f, 0.f};
    }
#pragma unroll
    for (int kt = 0; kt < 8; kt++) {
      short8_t a = ld8(&il[cur][c16 * 264 + kt * 32 + q * 8]);
#pragma unroll
      for (int g = 0; g < 3; g++) aI[g] = MFMA16(a, fi[g][kt], aI[g]);
    }
#pragma unroll
    for (int kt = 0; kt < 4; kt++) {
      short8_t a = ld8(&hl[cur][c16 * 136 + kt * 32 + q * 8]);
#pragma unroll
      for (int g = 0; g < 3; g++) aH[g] = MFMA16(a, fh[g][kt], aH[g]);
    }
#pragma unroll
    for (int rr = 0; rr < 4; rr++) {
      float r = sigm(aI[0][rr] + aH[0][rr] + brz[0]);
      float z = sigm(aI[1][rr] + aH[1][rr] + brz[1]);
      float n = tanh_fast(aI[2][rr] + bni + r * (aH[2][rr] + bnh));
      float hn = n + z * (h[rr] - n);
      h[rr] = hn;
      hl[nxt][(q * 4 + rr) * 136 + w * 16 + c16] = f2bf(hn);
    }
    if (s < 511)
      *reinterpret_cast<short8_t*>(&il[nxt][srow * 264 + sc * 8]) = iv;
    __syncthreads();
  }
#pragma unroll
  for (int rr = 0; rr < 4; rr++)
    HS[((size_t)(2 + dir) * 512 + b_base + b0l + q * 4 + rr) * 128 + w * 16 + c16] = h[rr];
}

// ------------------------------- decoder (verified R6) ----------------------
__global__ __launch_bounds__(256, 1) void k_dec(
    const float* __restrict__ x0save,        // (512)
    const float* __restrict__ HS,            // (4,512,128) = [l0f,l0b,l1f,l1b]
    const unsigned short* __restrict__ Whh,  // dec (2,2,384,128) bf16
    const unsigned short* __restrict__ Wih1, // dec (2,384,256) bf16
    const float* __restrict__ Wih0,          // dec (2,384,1) fp32
    const float* __restrict__ bih,           // (2,2,384)
    const float* __restrict__ bhh,           // (2,2,384)
    const float* __restrict__ fc_w,          // (256) fp32
    const float* __restrict__ fcb,           // (1)
    float* __restrict__ out) {               // (24,512)
  int b0 = blockIdx.x * 16;
  int tid = threadIdx.x, w = tid >> 6, lane = tid & 63, q = lane >> 4, c16 = lane & 15;
  __shared__ unsigned short hc0[16 * 264];
  __shared__ unsigned short hc1[16 * 264];
  __shared__ float x0s[16];
  __shared__ float fcwf[256];
  int jj = w * 32 + c16;   // actual h-column (biases, LDS addressing)
  int jw = w * 32;         // wave column base (MFMA B-frag row bases; +c16 at load)

  float hs[4][2][4];
#pragma unroll
  for (int cell = 0; cell < 4; cell++)
#pragma unroll
    for (int cc = 0; cc < 2; cc++)
#pragma unroll
      for (int rr = 0; rr < 4; rr++) {
        int row = q * 4 + rr, j = jj + cc * 16;
        float v = HS[((size_t)cell * 512 + b0 + row) * 128 + j];
        hs[cell][cc][rr] = v;
        unsigned short bv = f2bf(v);
        unsigned short* tile = (cell < 2) ? hc0 : hc1;
        tile[row * 264 + (cell & 1) * 128 + j] = bv;
      }
  if (tid < 16) x0s[tid] = x0save[b0 + tid];
  fcwf[tid] = fc_w[tid];

  float w0c[2][2][3], bi0[2][2][3], bh0[2][2][3], bi1[2][2][3], bh1[2][2][3];
#pragma unroll
  for (int d = 0; d < 2; d++)
#pragma unroll
    for (int cc = 0; cc < 2; cc++)
#pragma unroll
      for (int g = 0; g < 3; g++) {
        int col = g * 128 + jj + cc * 16;
        w0c[d][cc][g] = Wih0[d * 384 + col];
        bi0[d][cc][g] = bih[d * 384 + col];
        bh0[d][cc][g] = bhh[d * 384 + col];
        bi1[d][cc][g] = bih[(2 + d) * 384 + col];
        bh1[d][cc][g] = bhh[(2 + d) * 384 + col];
      }
  __syncthreads();

  for (int st = 0; st < 24; st++) {
    // ---- layer 0 (input = scalar x0, two cells) ----
    float hn0[2][2][4];
#pragma unroll
    for (int d = 0; d < 2; d++) {
      const unsigned short* Wd = Whh + (size_t)d * 384 * 128;
      short8_t a0[4];
#pragma unroll
      for (int kt = 0; kt < 4; kt++)
        a0[kt] = ld8(&hc0[c16 * 264 + d * 128 + kt * 32 + q * 8]);
      f32x4_t acc[6];
#pragma unroll
      for (int f = 0; f < 6; f++) acc[f] = (f32x4_t){0.f, 0.f, 0.f, 0.f};
#pragma unroll
      for (int kt = 0; kt < 4; kt++)
#pragma unroll
        for (int g = 0; g < 3; g++)
#pragma unroll
          for (int cc = 0; cc < 2; cc++) {
            int f = g * 2 + cc, n0 = g * 128 + jw + cc * 16;
            acc[f] = MFMA16(a0[kt], ld8(Wd + (size_t)(n0 + c16) * 128 + kt * 32 + q * 8), acc[f]);
          }
#pragma unroll
      for (int cc = 0; cc < 2; cc++)
#pragma unroll
        for (int rr = 0; rr < 4; rr++) {
          float xin = x0s[q * 4 + rr];
          float r = sigm(xin * w0c[d][cc][0] + bi0[d][cc][0] + acc[cc][rr] + bh0[d][cc][0]);
          float z = sigm(xin * w0c[d][cc][1] + bi0[d][cc][1] + acc[2 + cc][rr] + bh0[d][cc][1]);
          float n = tanh_fast(xin * w0c[d][cc][2] + bi0[d][cc][2] +
                              r * (acc[4 + cc][rr] + bh0[d][cc][2]));
          float hv = n + z * (hs[d][cc][rr] - n);
          hn0[d][cc][rr] = hv;
          hs[d][cc][rr] = hv;
        }
    }
    __syncthreads();
#pragma unroll
    for (int d = 0; d < 2; d++)
#pragma unroll
      for (int cc = 0; cc < 2; cc++)
#pragma unroll
        for (int rr = 0; rr < 4; rr++)
          hc0[(q * 4 + rr) * 264 + d * 128 + jj + cc * 16] = f2bf(hn0[d][cc][rr]);
    __syncthreads();

    // ---- layer 1 (input = hc0 concat, two cells) ----
    short8_t ai[8];
#pragma unroll
    for (int kt = 0; kt < 8; kt++) ai[kt] = ld8(&hc0[c16 * 264 + kt * 32 + q * 8]);
    float hn1[2][2][4];
#pragma unroll
    for (int d = 0; d < 2; d++) {
      const unsigned short* Wh = Whh + (size_t)(2 + d) * 384 * 128;
      const unsigned short* Wi = Wih1 + (size_t)d * 384 * 256;
      short8_t ah[4];
#pragma unroll
      for (int kt = 0; kt < 4; kt++)
        ah[kt] = ld8(&hc1[c16 * 264 + d * 128 + kt * 32 + q * 8]);
      f32x4_t aRZ[4], aNi[2], aNh[2];
#pragma unroll
      for (int f = 0; f < 4; f++) aRZ[f] = (f32x4_t){0.f, 0.f, 0.f, 0.f};
#pragma unroll
      for (int cc = 0; cc < 2; cc++) {
        aNi[cc] = (f32x4_t){0.f, 0.f, 0.f, 0.f};
        aNh[cc] = (f32x4_t){0.f, 0.f, 0.f, 0.f};
      }
#pragma unroll
      for (int kt = 0; kt < 8; kt++) {
#pragma unroll
        for (int f = 0; f < 4; f++) {
          int n0 = (f >> 1) * 128 + jw + (f & 1) * 16;
          aRZ[f] = MFMA16(ai[kt], ld8(Wi + (size_t)(n0 + c16) * 256 + kt * 32 + q * 8), aRZ[f]);
        }
#pragma unroll
        for (int cc = 0; cc < 2; cc++) {
          int n0 = 256 + jw + cc * 16;
          aNi[cc] = MFMA16(ai[kt], ld8(Wi + (size_t)(n0 + c16) * 256 + kt * 32 + q * 8), aNi[cc]);
        }
      }
#pragma unroll
      for (int kt = 0; kt < 4; kt++) {
#pragma unroll
        for (int f = 0; f < 4; f++) {
          int n0 = (f >> 1) * 128 + jw + (f & 1) * 16;
          aRZ[f] = MFMA16(ah[kt], ld8(Wh + (size_t)(n0 + c16) * 128 + kt * 32 + q * 8), aRZ[f]);
        }
#pragma unroll
        for (int cc = 0; cc < 2; cc++) {
          int n0 = 256 + jw + cc * 16;
          aNh[cc] = MFMA16(ah[kt], ld8(Wh + (size_t)(n0 + c16) * 128 + kt * 32 + q * 8), aNh[cc]);
        }
      }
#pragma unroll
      for (int cc = 0; cc < 2; cc++)
#pragma unroll
        for (int rr = 0; rr < 4; rr++) {
          float r = sigm(aRZ[cc][rr] + bi1[d][cc][0] + bh1[d][cc][0]);
          float z = sigm(aRZ[2 + cc][rr] + bi1[d][cc][1] + bh1[d][cc][1]);
          float n = tanh_fast(aNi[cc][rr] + bi1[d][cc][2] + r * (aNh[cc][rr] + bh1[d][cc][2]));
          float hv = n + z * (hs[2 + d][cc][rr] - n);
          hn1[d][cc][rr] = hv;
          hs[2 + d][cc][rr] = hv;
        }
    }
    __syncthreads();
#pragma unroll
    for (int d = 0; d < 2; d++)
#pragma unroll
      for (int cc = 0; cc < 2; cc++)
#pragma unroll
        for (int rr = 0; rr < 4; rr++)
          hc1[(q * 4 + rr) * 264 + d * 128 + jj + cc * 16] = f2bf(hn1[d][cc][rr]);
    __syncthreads();

    // ---- fc -> pred, feed back (wave 0 only) ----
    if (w == 0) {
      float s = 0.f;
#pragma unroll
      for (int i = 0; i < 8; i++) {
        short8_t hv = ld8(&hc1[c16 * 264 + q * 64 + i * 8]);
#pragma unroll
        for (int e = 0; e < 8; e++)
          s += bf2f((unsigned short)hv[e]) * fcwf[q * 64 + i * 8 + e];
      }
      s += __shfl_xor(s, 16);
      s += __shfl_xor(s, 32);
      if (q == 0) {
        float pred = s + fcb[0];
        x0s[c16] = pred;
        out[(size_t)st * 512 + b0 + c16] = pred;
      }
    }
    __syncthreads();
  }
}

// ---------------------------------------------------------------------------
extern "C" void kernel_launch(void* const* d_in, const int* in_sizes, int n_in,
                              void* d_out, int out_size, void* d_ws, size_t ws_size,
                              hipStream_t stream) {
  const float* x     = (const float*)d_in[0];
  const float* eWih0 = (const float*)d_in[1];
  const float* eWih1 = (const float*)d_in[2];
  const float* eWhh  = (const float*)d_in[3];
  const float* ebih  = (const float*)d_in[4];
  const float* ebhh  = (const float*)d_in[5];
  const float* dWih0 = (const float*)d_in[6];
  const float* dWih1 = (const float*)d_in[7];
  const float* dWhh  = (const float*)d_in[8];
  const float* dbih  = (const float*)d_in[9];
  const float* dbhh  = (const float*)d_in[10];
  const float* fc_w  = (const float*)d_in[11];
  const float* fc_b  = (const float*)d_in[12];
  float* out = (float*)d_out;
  (void)in_sizes; (void)n_in; (void)out_size;

  // ---- ws-keyed chunk ladder: OutF = Bc*131072 bytes; proven ws >= ~48MB ---
  const size_t fixedB = 2048 + 1048576 + 393216 + 393216 + 4096;
  int Bc = 128;
  if (fixedB + (size_t)512 * 131072 <= ws_size)      Bc = 512;  // 68.9MB total
  else if (fixedB + (size_t)256 * 131072 <= ws_size) Bc = 256;  // 35.4MB total
  // (Bc=128 floor: 18.6MB — always fits given R6 evidence)

  char* ws = (char*)d_ws;
  size_t off = 0;
  auto alloc = [&](size_t bytes) -> char* {
    off = (off + 255) & ~(size_t)255;
    char* p = ws + off;
    off += bytes;
    return p;
  };
  float* x0save          = (float*)alloc(2048);
  float* HS              = (float*)alloc(1048576);
  unsigned short* bdWih1 = (unsigned short*)alloc(393216);   // 196608 elems
  unsigned short* bdWhh  = (unsigned short*)alloc(393216);   // 196608 elems
  unsigned short* OutF   = (unsigned short*)alloc((size_t)Bc * 131072);
  unsigned short* OutB   = (unsigned short*)d_in[0];   // byte-exact x overlay

  k_prep<<<194, 256, 0, stream>>>(x, dWih1, dWhh, bdWih1, bdWhh, x0save);

  const float* Whh1 = eWhh + (size_t)2 * 384 * 128;
  int nchunks = 512 / Bc;
  for (int c = 0; c < nchunks; c++) {
    int b_base = c * Bc;
    k_scan0<<<dim3(Bc / 16), 256, 0, stream>>>(x, eWih0, ebih, eWhh, ebhh,
                                               OutF, HS, b_base, 0, Bc);
    k_scan0<<<dim3(Bc / 16), 256, 0, stream>>>(x, eWih0, ebih, eWhh, ebhh,
                                               OutB, HS, b_base, 1, 512);
    k_scan1<<<dim3(Bc / 16, 2), 512, 0, stream>>>(OutF, OutB, eWih1, ebih + 768,
                                                  Whh1, ebhh + 768, HS, b_base, Bc);
  }
  k_dec<<<dim3(32), 256, 0, stream>>>(x0save, HS, bdWhh, bdWih1, dWih0, dbih, dbhh,
                                      fc_w, fc_b, out);
}